// Round 8
// baseline (112.495 us; speedup 1.0000x reference)
//
#include <hip/hip_runtime.h>
#include <hip/hip_bf16.h>

#define SEQ 8192
#define HD 128
#define BM 128
#define BN 64
#define NQT (SEQ / BM)   // 64
#define THREADS 256

typedef __bf16 bf16_t;
typedef __bf16 bf16x2 __attribute__((ext_vector_type(2)));
typedef __bf16 bf16x8 __attribute__((ext_vector_type(8)));
typedef float f32x4 __attribute__((ext_vector_type(4)));
typedef float f32x16 __attribute__((ext_vector_type(16)));
typedef unsigned int u32x4 __attribute__((ext_vector_type(4)));

#if __has_builtin(__builtin_amdgcn_exp2f)
__device__ inline float exp2_fast(float x) { return __builtin_amdgcn_exp2f(x); }
#else
__device__ inline float exp2_fast(float x) { return exp2f(x); }
#endif

// async global->LDS DMA, 16 B per lane; lds dest wave-uniform, HW adds lane*16
__device__ inline void load_lds16(const void* g, void* l) {
  __builtin_amdgcn_global_load_lds(
      (const __attribute__((address_space(1))) void*)g,
      (__attribute__((address_space(3))) void*)l, 16, 0, 0);
}

// ---------------- prep ----------------
// Kb blocked: [tile T][d-chunk c 0..15][key r 0..63][8]  = K[T*64+r][c*8+j]
// VT blocked: [tile T][key-chunk kc 0..7][d 0..127][8]   = V[T*64+kc*8+j][d]
__global__ __launch_bounds__(256) void prep_kernel(const float* __restrict__ K,
                                                   const float* __restrict__ V,
                                                   bf16_t* __restrict__ Kb,
                                                   bf16_t* __restrict__ VT) {
  const int b = (int)blockIdx.x;
  const int tid = (int)threadIdx.x;
  if (b < 256) {
    // V tile: 64 keys x 64 d, staged f32 in LDS (coalesced reads)
    __shared__ float tile[64][65];
    const int T = b & 127;
    const int d0 = (b >> 7) * 64;
    const int s0 = T * 64;
    const int r = tid >> 2;          // 0..63 (key)
    const int c0 = (tid & 3) * 16;   // d offset
#pragma unroll
    for (int j4 = 0; j4 < 4; ++j4) {
      float4 x = *(const float4*)&V[(size_t)(s0 + r) * HD + d0 + c0 + j4 * 4];
      tile[r][c0 + j4 * 4 + 0] = x.x;
      tile[r][c0 + j4 * 4 + 1] = x.y;
      tile[r][c0 + j4 * 4 + 2] = x.z;
      tile[r][c0 + j4 * 4 + 3] = x.w;
    }
    __syncthreads();
    const int d_l = tid & 63;
    const int kc0 = (tid >> 6) * 2;  // 0,2,4,6
#pragma unroll
    for (int k2 = 0; k2 < 2; ++k2) {
      const int kc = kc0 + k2;
      bf16x8 wv;
#pragma unroll
      for (int j = 0; j < 8; ++j) wv[j] = (bf16_t)tile[kc * 8 + j][d_l];
      *(bf16x8*)&VT[((size_t)(T * 8 + kc) * 128 + d0 + d_l) * 8] = wv;
    }
  } else {
    // K convert: one 16B chunk per thread
    const int base = (b - 256) * 2048 + tid * 8;   // flat over 8192*128
    const int row = base >> 7;
    const int c = (base >> 3) & 15;
    const int T = row >> 6;
    const int r = row & 63;
    float4 a = *(const float4*)&K[base];
    float4 cc = *(const float4*)&K[base + 4];
    bf16x8 f;
    f[0] = (bf16_t)a.x; f[1] = (bf16_t)a.y; f[2] = (bf16_t)a.z; f[3] = (bf16_t)a.w;
    f[4] = (bf16_t)cc.x; f[5] = (bf16_t)cc.y; f[6] = (bf16_t)cc.z; f[7] = (bf16_t)cc.w;
    *(bf16x8*)&Kb[((size_t)(T * 16 + c) * 64 + r) * 8] = f;
  }
}

// ---------------- main flash-attention kernel ----------------
// R7 (resubmit after infra failure): BM=128, 4 waves/block, 2 INDEPENDENT
// blocks per CU (80 KB LDS each = exactly 160 KB). Per-wave code identical
// to R6 (cross-tile pipeline: DMA(it+1); QK^T(it) grouped; PV(it-1) chunks
// textually interleaved with exp/pack(it); one barrier/iter). The only
// change vs R6: the two 4-wave groups on a CU have SEPARATE barriers, so
// when one group drains vmcnt at its __syncthreads, the other keeps
// feeding the matrix pipe (m114 mechanism). Each wave stages 4 K + 4 V
// DMA regions per buffer (rr0 = w*4).
__global__ __launch_bounds__(THREADS, 2) void fattn_kernel(
    const float* __restrict__ Q, const bf16_t* __restrict__ Kb,
    const bf16_t* __restrict__ VT, float* __restrict__ Opart,
    float* __restrict__ Lpart, int kshift, int nit) {
  __shared__ __align__(16) bf16_t kt2[2][16][64][8];  // 32 KB [buf][d-chunk][key][8]
  __shared__ __align__(16) bf16_t vt3[3][8][128][8];  // 48 KB [buf][key-chunk][d][8]

  const int tid = (int)threadIdx.x;
  const int lane = tid & 63;
  const int w = tid >> 6;          // q-group 0..3
  const int h = lane >> 5;
  const int n32 = lane & 31;

  const int qt = (int)blockIdx.x >> kshift;
  const int sp = (int)blockIdx.x & ((1 << kshift) - 1);
  const int qbase = qt * BM;
  const int tile0 = sp * nit;          // first 64-key tile index

  const float SC2 = 0.08838834764831845f * 1.4426950408889634f; // (1/sqrt(128))*log2e

  // Q B-frags (n = n32 = q-row, k-dim = d), pre-scaled
  bf16x8 qf[8];
  {
    const float* qp = Q + (size_t)(qbase + w * 32 + n32) * HD + h * 8;
#pragma unroll
    for (int kk = 0; kk < 8; ++kk) {
      float4 a = *(const float4*)(qp + kk * 16);
      float4 b = *(const float4*)(qp + kk * 16 + 4);
      bf16x8 f;
      f[0] = (bf16_t)(a.x * SC2); f[1] = (bf16_t)(a.y * SC2);
      f[2] = (bf16_t)(a.z * SC2); f[3] = (bf16_t)(a.w * SC2);
      f[4] = (bf16_t)(b.x * SC2); f[5] = (bf16_t)(b.y * SC2);
      f[6] = (bf16_t)(b.z * SC2); f[7] = (bf16_t)(b.w * SC2);
      qf[kk] = f;
    }
  }

  f32x16 o_acc[4];   // O[32q x 128d]
#pragma unroll
  for (int i = 0; i < 4; ++i)
#pragma unroll
    for (int e = 0; e < 16; ++e) o_acc[i][e] = 0.f;
  float l_acc = 0.f;

  bf16x8 paA[4], paB[4];   // P A-frags for one 64-key tile (alternating)

  const int rr0 = w * 4;   // DMA region indices rr0..rr0+3 (4 waves x 4 = 16)

// exp -> pack -> half-wave exchange -> ONE PV A-frag (16 keys) from one
// sacc half; produces PDST_EXPR in-lane.
#define EXPPACK1(SACC, KK2, PDST_EXPR)                                     \
  {                                                                        \
    float pf[8];                                                           \
    _Pragma("unroll")                                                      \
    for (int j = 0; j < 8; ++j) pf[j] = exp2_fast((SACC)[8 * (KK2) + j]);  \
    l_acc += ((pf[0] + pf[1]) + (pf[2] + pf[3])) +                         \
             ((pf[4] + pf[5]) + (pf[6] + pf[7]));                          \
    bf16x2 p0, p1, p2, p3;                                                 \
    p0[0] = (bf16_t)pf[0]; p0[1] = (bf16_t)pf[1];                          \
    p1[0] = (bf16_t)pf[2]; p1[1] = (bf16_t)pf[3];                          \
    p2[0] = (bf16_t)pf[4]; p2[1] = (bf16_t)pf[5];                          \
    p3[0] = (bf16_t)pf[6]; p3[1] = (bf16_t)pf[7];                          \
    const unsigned int sA = __builtin_bit_cast(unsigned int, p0);          \
    const unsigned int sB = __builtin_bit_cast(unsigned int, p1);          \
    const unsigned int sC = __builtin_bit_cast(unsigned int, p2);          \
    const unsigned int sD = __builtin_bit_cast(unsigned int, p3);          \
    unsigned int s0 = h ? sA : sC, s1 = h ? sB : sD;                       \
    unsigned int r0 = __shfl_xor(s0, 32);                                  \
    unsigned int r1 = __shfl_xor(s1, 32);                                  \
    unsigned int o0 = h ? sC : sA, o1 = h ? sD : sB;                       \
    u32x4 fv;                                                              \
    fv[0] = h ? r0 : o0; fv[1] = h ? r1 : o1;                              \
    fv[2] = h ? o0 : r0; fv[3] = h ? o1 : r1;                              \
    (PDST_EXPR) = __builtin_bit_cast(bf16x8, fv);                          \
  }

// one PV chunk: 16 keys (frag PP[C]) x all 128 d -> 4 MFMA
#define PVC(PP, C)                                                         \
  _Pragma("unroll")                                                        \
  for (int ot = 0; ot < 4; ++ot) {                                         \
    bf16x8 vb = *(const bf16x8*)&vt3[vp][(C) * 2 + h][ot * 32 + n32][0];   \
    o_acc[ot] = __builtin_amdgcn_mfma_f32_32x32x16_bf16(PP[C], vb, o_acc[ot], 0, 0, 0); \
  }

// pipelined body for iteration IT>=1: DMA(IT+1); QK^T(IT) from kt2[KC]
// (sacc0 group first so it's ready early); then 4x [PV(IT-1) chunk ||
// exp(IT) chunk]; barrier.  KC is a literal.
#define FBODY(IT, PPREV, PCUR, KC)                                         \
  {                                                                        \
    const int it_ = (IT);                                                  \
    if (it_ + 1 < nit) {                                                   \
      const int ntile = tile0 + it_ + 1;                                   \
      _Pragma("unroll")                                                    \
      for (int t = 0; t < 4; ++t) {                                        \
        const int rr = rr0 + t;                                            \
        load_lds16(Kb + ((size_t)(ntile * 16 + rr) * 64 + lane) * 8,       \
                   (char*)&kt2[(KC) ^ 1][0][0][0] + rr * 1024);            \
        load_lds16(VT + ((size_t)(ntile * 8 + (rr >> 1)) * 128 + (rr & 1) * 64 + lane) * 8, \
                   (char*)&vt3[vd][0][0][0] + rr * 1024);                  \
      }                                                                    \
    }                                                                      \
    f32x16 sacc0, sacc1;                                                   \
    _Pragma("unroll")                                                      \
    for (int e = 0; e < 16; ++e) { sacc0[e] = 0.f; sacc1[e] = 0.f; }       \
    _Pragma("unroll")                                                      \
    for (int kk = 0; kk < 8; ++kk) {                                       \
      bf16x8 af0 = *(const bf16x8*)&kt2[KC][2 * kk + h][n32][0];           \
      sacc0 = __builtin_amdgcn_mfma_f32_32x32x16_bf16(af0, qf[kk], sacc0, 0, 0, 0); \
    }                                                                      \
    _Pragma("unroll")                                                      \
    for (int kk = 0; kk < 8; ++kk) {                                       \
      bf16x8 af1 = *(const bf16x8*)&kt2[KC][2 * kk + h][32 + n32][0];      \
      sacc1 = __builtin_amdgcn_mfma_f32_32x32x16_bf16(af1, qf[kk], sacc1, 0, 0, 0); \
    }                                                                      \
    PVC(PPREV, 0) EXPPACK1(sacc0, 0, PCUR[0])                              \
    PVC(PPREV, 1) EXPPACK1(sacc0, 1, PCUR[1])                              \
    PVC(PPREV, 2) EXPPACK1(sacc1, 0, PCUR[2])                              \
    PVC(PPREV, 3) EXPPACK1(sacc1, 1, PCUR[3])                              \
    vp = (vp + 1 == 3) ? 0 : vp + 1;                                       \
    vd = (vd + 1 == 3) ? 0 : vd + 1;                                       \
    __syncthreads();                                                       \
  }

  // ---- prologue: DMA tile0 -> kt[0], vt[0] ----
#pragma unroll
  for (int t = 0; t < 4; ++t) {
    const int rr = rr0 + t;
    load_lds16(Kb + ((size_t)(tile0 * 16 + rr) * 64 + lane) * 8,
               (char*)&kt2[0][0][0][0] + rr * 1024);
    load_lds16(VT + ((size_t)(tile0 * 8 + (rr >> 1)) * 128 + (rr & 1) * 64 + lane) * 8,
               (char*)&vt3[0][0][0][0] + rr * 1024);
  }
  __syncthreads();

  // ---- peel it=0: DMA tile1 -> kt[1], vt[1]; QK^T(0); exp -> paA ----
  {
    if (nit > 1) {
      const int ntile = tile0 + 1;
#pragma unroll
      for (int t = 0; t < 4; ++t) {
        const int rr = rr0 + t;
        load_lds16(Kb + ((size_t)(ntile * 16 + rr) * 64 + lane) * 8,
                   (char*)&kt2[1][0][0][0] + rr * 1024);
        load_lds16(VT + ((size_t)(ntile * 8 + (rr >> 1)) * 128 + (rr & 1) * 64 + lane) * 8,
                   (char*)&vt3[1][0][0][0] + rr * 1024);
      }
    }
    f32x16 sacc0, sacc1;
#pragma unroll
    for (int e = 0; e < 16; ++e) { sacc0[e] = 0.f; sacc1[e] = 0.f; }
#pragma unroll
    for (int kk = 0; kk < 8; ++kk) {
      bf16x8 af0 = *(const bf16x8*)&kt2[0][2 * kk + h][n32][0];
      sacc0 = __builtin_amdgcn_mfma_f32_32x32x16_bf16(af0, qf[kk], sacc0, 0, 0, 0);
    }
#pragma unroll
    for (int kk = 0; kk < 8; ++kk) {
      bf16x8 af1 = *(const bf16x8*)&kt2[0][2 * kk + h][32 + n32][0];
      sacc1 = __builtin_amdgcn_mfma_f32_32x32x16_bf16(af1, qf[kk], sacc1, 0, 0, 0);
    }
    EXPPACK1(sacc0, 0, paA[0])
    EXPPACK1(sacc0, 1, paA[1])
    EXPPACK1(sacc1, 0, paA[2])
    EXPPACK1(sacc1, 1, paA[3])
    __syncthreads();
  }

  int vp = 0;   // vt3 index holding tile (IT-1) for IT=1
  int vd = 2;   // vt3 index receiving tile (IT+1) for IT=1

  // nit is always even; bodies 1..nit-2 in pairs (KC literal by parity),
  // leftover body nit-1 (odd -> KC=1).
  for (int it = 1; it + 1 <= nit - 1; it += 2) {
    FBODY(it, paA, paB, 1)
    FBODY(it + 1, paB, paA, 0)
  }
  FBODY(nit - 1, paA, paB, 1)

  // ---- tail: PV(nit-1) using paB, vt3[vp] ----
#pragma unroll
  for (int C = 0; C < 4; ++C) {
#pragma unroll
    for (int ot = 0; ot < 4; ++ot) {
      bf16x8 vb = *(const bf16x8*)&vt3[vp][C * 2 + h][ot * 32 + n32][0];
      o_acc[ot] = __builtin_amdgcn_mfma_f32_32x32x16_bf16(paB[C], vb, o_acc[ot], 0, 0, 0);
    }
  }

#undef FBODY
#undef PVC
#undef EXPPACK1

  // ---- epilogue: O block store + L (all intra-wave) ----
  {
    float* op = Opart + ((size_t)sp * SEQ + qbase + w * 32) * HD;
#pragma unroll
    for (int ot = 0; ot < 4; ++ot)
#pragma unroll
      for (int reg = 0; reg < 16; ++reg) {
        const int row = (reg & 3) + 8 * (reg >> 2) + 4 * h;
        op[row * HD + ot * 32 + n32] = o_acc[ot][reg];
      }
    float l = l_acc + __shfl_xor(l_acc, 32);   // combine the two key-halves
    if (lane < 32)
      Lpart[(size_t)sp * SEQ + qbase + w * 32 + n32] = l;
  }
}

// ---------------- combine: out = sum_s O_s / sum_s l_s ----------------
__global__ __launch_bounds__(256) void combine_kernel(const float* __restrict__ Opart,
                                                      const float* __restrict__ Lpart,
                                                      float* __restrict__ out, int ksplit) {
  const int tid = (int)threadIdx.x;
  const int row = (int)blockIdx.x * 8 + (tid >> 5);
  const int c0 = (tid & 31) * 4;
  float lsum = 0.f;
  for (int s = 0; s < ksplit; ++s) lsum += Lpart[(size_t)s * SEQ + row];
  f32x4 acc;
#pragma unroll
  for (int e = 0; e < 4; ++e) acc[e] = 0.f;
  for (int s = 0; s < ksplit; ++s) {
    f32x4 o = *(const f32x4*)&Opart[((size_t)s * SEQ + row) * HD + c0];
#pragma unroll
    for (int e = 0; e < 4; ++e) acc[e] += o[e];
  }
  const float inv = 1.0f / lsum;
  f32x4 res;
#pragma unroll
  for (int e = 0; e < 4; ++e) res[e] = acc[e] * inv;
  *(f32x4*)&out[(size_t)row * HD + c0] = res;
}

extern "C" void kernel_launch(void* const* d_in, const int* in_sizes, int n_in,
                              void* d_out, int out_size, void* d_ws, size_t ws_size,
                              hipStream_t stream) {
  const float* Q = (const float*)d_in[0];
  const float* K = (const float*)d_in[1];
  const float* V = (const float*)d_in[2];
  float* out = (float*)d_out;

  int ksplit = 8, kshift = 3;
  while (ksplit > 1) {
    size_t need = (size_t)ksplit * SEQ * HD * 4
                + (size_t)ksplit * SEQ * 4
                + (size_t)SEQ * HD * 2 * 2;
    if (need <= ws_size) break;
    ksplit >>= 1; kshift--;
  }

  char* ws = (char*)d_ws;
  float* Opart = (float*)ws;
  float* Lpart = (float*)(ws + (size_t)ksplit * SEQ * HD * 4);
  bf16_t* Kb = (bf16_t*)(ws + (size_t)ksplit * SEQ * HD * 4 + (size_t)ksplit * SEQ * 4);
  bf16_t* VT = Kb + (size_t)SEQ * HD;

  const int nit = SEQ / (ksplit * BN);

  prep_kernel<<<768, 256, 0, stream>>>(K, V, Kb, VT);
  fattn_kernel<<<NQT * ksplit, THREADS, 0, stream>>>(Q, Kb, VT, Opart, Lpart, kshift, nit);
  combine_kernel<<<SEQ / 8, 256, 0, stream>>>(Opart, Lpart, out, ksplit);
}

// Round 9
// 110.274 us; speedup vs baseline: 1.0201x; 1.0201x over previous
//
#include <hip/hip_runtime.h>
#include <hip/hip_bf16.h>

#define SEQ 8192
#define HD 128
#define BM 256
#define BN 64
#define NQT (SEQ / BM)   // 32
#define THREADS 512

typedef __bf16 bf16_t;
typedef __bf16 bf16x2 __attribute__((ext_vector_type(2)));
typedef __bf16 bf16x8 __attribute__((ext_vector_type(8)));
typedef float f32x4 __attribute__((ext_vector_type(4)));
typedef float f32x16 __attribute__((ext_vector_type(16)));
typedef unsigned int u32x4 __attribute__((ext_vector_type(4)));

#if __has_builtin(__builtin_amdgcn_exp2f)
__device__ inline float exp2_fast(float x) { return __builtin_amdgcn_exp2f(x); }
#else
__device__ inline float exp2_fast(float x) { return exp2f(x); }
#endif

// v_permlane32_swap_b32: a.hi32lanes <-> b.lo32lanes (one VALU op; replaces
// ds_bpermute round-trip + cndmask selects for the half-wave exchange).
__device__ inline void permswap32(unsigned int& a, unsigned int& b) {
#if __has_builtin(__builtin_amdgcn_permlane32_swap)
  auto r = __builtin_amdgcn_permlane32_swap(a, b, false, false);
  a = (unsigned int)r[0];
  b = (unsigned int)r[1];
#else
  asm volatile("v_permlane32_swap_b32 %0, %1" : "+v"(a), "+v"(b));
#endif
}

// async global->LDS DMA, 16 B per lane; lds dest wave-uniform, HW adds lane*16
__device__ inline void load_lds16(const void* g, void* l) {
  __builtin_amdgcn_global_load_lds(
      (const __attribute__((address_space(1))) void*)g,
      (__attribute__((address_space(3))) void*)l, 16, 0, 0);
}

// ---------------- prep ----------------
// Kb blocked: [tile T][d-chunk c 0..15][key r 0..63][8]  = K[T*64+r][c*8+j]
// VT blocked: [tile T][key-chunk kc 0..7][d 0..127][8]   = V[T*64+kc*8+j][d]
__global__ __launch_bounds__(256) void prep_kernel(const float* __restrict__ K,
                                                   const float* __restrict__ V,
                                                   bf16_t* __restrict__ Kb,
                                                   bf16_t* __restrict__ VT) {
  const int b = (int)blockIdx.x;
  const int tid = (int)threadIdx.x;
  if (b < 256) {
    // V tile: 64 keys x 64 d, staged f32 in LDS (coalesced reads)
    __shared__ float tile[64][65];
    const int T = b & 127;
    const int d0 = (b >> 7) * 64;
    const int s0 = T * 64;
    const int r = tid >> 2;          // 0..63 (key)
    const int c0 = (tid & 3) * 16;   // d offset
#pragma unroll
    for (int j4 = 0; j4 < 4; ++j4) {
      float4 x = *(const float4*)&V[(size_t)(s0 + r) * HD + d0 + c0 + j4 * 4];
      tile[r][c0 + j4 * 4 + 0] = x.x;
      tile[r][c0 + j4 * 4 + 1] = x.y;
      tile[r][c0 + j4 * 4 + 2] = x.z;
      tile[r][c0 + j4 * 4 + 3] = x.w;
    }
    __syncthreads();
    const int d_l = tid & 63;
    const int kc0 = (tid >> 6) * 2;  // 0,2,4,6
#pragma unroll
    for (int k2 = 0; k2 < 2; ++k2) {
      const int kc = kc0 + k2;
      bf16x8 wv;
#pragma unroll
      for (int j = 0; j < 8; ++j) wv[j] = (bf16_t)tile[kc * 8 + j][d_l];
      *(bf16x8*)&VT[((size_t)(T * 8 + kc) * 128 + d0 + d_l) * 8] = wv;
    }
  } else {
    // K convert: one 16B chunk per thread
    const int base = (b - 256) * 2048 + tid * 8;   // flat over 8192*128
    const int row = base >> 7;
    const int c = (base >> 3) & 15;
    const int T = row >> 6;
    const int r = row & 63;
    float4 a = *(const float4*)&K[base];
    float4 cc = *(const float4*)&K[base + 4];
    bf16x8 f;
    f[0] = (bf16_t)a.x; f[1] = (bf16_t)a.y; f[2] = (bf16_t)a.z; f[3] = (bf16_t)a.w;
    f[4] = (bf16_t)cc.x; f[5] = (bf16_t)cc.y; f[6] = (bf16_t)cc.z; f[7] = (bf16_t)cc.w;
    *(bf16x8*)&Kb[((size_t)(T * 16 + c) * 64 + r) * 8] = f;
  }
}

// ---------------- main flash-attention kernel ----------------
// BM=256, 8 waves, wave w owns 32 q-rows x all keys x all d. Cross-tile
// pipeline (R5/R6): iteration it does DMA(it+1), QK^T(it), PV(it-1) chunks
// textually interleaved with exp/pack(it), one barrier/iter.
// R9 changes: (1) the half-wave P exchange uses v_permlane32_swap_b32
// (pure VALU) instead of 2x __shfl_xor (ds_bpermute round-trip + lgkm
// stall) + ~12 v_cndmask per chunk -- removes 8 dependent LDS round-trips
// per wave-iter from the critical path; (2) QK^T sacc0/sacc1 chains are
// interleaved (two independent accumulator chains, no dep-latency bubbles).
__global__ __launch_bounds__(THREADS, 2) void fattn_kernel(
    const float* __restrict__ Q, const bf16_t* __restrict__ Kb,
    const bf16_t* __restrict__ VT, float* __restrict__ Opart,
    float* __restrict__ Lpart, int kshift, int nit) {
  __shared__ __align__(16) bf16_t kt2[2][16][64][8];  // 32 KB [buf][d-chunk][key][8]
  __shared__ __align__(16) bf16_t vt3[3][8][128][8];  // 48 KB [buf][key-chunk][d][8]

  const int tid = (int)threadIdx.x;
  const int lane = tid & 63;
  const int w = tid >> 6;          // q-group 0..7
  const int h = lane >> 5;
  const int n32 = lane & 31;

  const int qt = (int)blockIdx.x >> kshift;
  const int sp = (int)blockIdx.x & ((1 << kshift) - 1);
  const int qbase = qt * BM;
  const int tile0 = sp * nit;          // first 64-key tile index

  const float SC2 = 0.08838834764831845f * 1.4426950408889634f; // (1/sqrt(128))*log2e

  // Q B-frags (n = n32 = q-row, k-dim = d), pre-scaled
  bf16x8 qf[8];
  {
    const float* qp = Q + (size_t)(qbase + w * 32 + n32) * HD + h * 8;
#pragma unroll
    for (int kk = 0; kk < 8; ++kk) {
      float4 a = *(const float4*)(qp + kk * 16);
      float4 b = *(const float4*)(qp + kk * 16 + 4);
      bf16x8 f;
      f[0] = (bf16_t)(a.x * SC2); f[1] = (bf16_t)(a.y * SC2);
      f[2] = (bf16_t)(a.z * SC2); f[3] = (bf16_t)(a.w * SC2);
      f[4] = (bf16_t)(b.x * SC2); f[5] = (bf16_t)(b.y * SC2);
      f[6] = (bf16_t)(b.z * SC2); f[7] = (bf16_t)(b.w * SC2);
      qf[kk] = f;
    }
  }

  f32x16 o_acc[4];   // O[32q x 128d]
#pragma unroll
  for (int i = 0; i < 4; ++i)
#pragma unroll
    for (int e = 0; e < 16; ++e) o_acc[i][e] = 0.f;
  float l_acc = 0.f;

  bf16x8 paA[4], paB[4];   // P A-frags for one 64-key tile (alternating)

  const int rr0 = w * 2;   // DMA region indices rr0, rr0+1

// exp -> pack -> permlane32_swap exchange -> ONE PV A-frag (16 keys).
// (fv0,fv2) = swap(sA,sC): fv0 = [sA.lo|sC.lo], fv2 = [sA.hi|sC.hi];
// (fv1,fv3) = swap(sB,sD). Verified against the shfl_xor mapping.
#define EXPPACK1(SACC, KK2, PDST_EXPR)                                     \
  {                                                                        \
    float pf[8];                                                           \
    _Pragma("unroll")                                                      \
    for (int j = 0; j < 8; ++j) pf[j] = exp2_fast((SACC)[8 * (KK2) + j]);  \
    l_acc += ((pf[0] + pf[1]) + (pf[2] + pf[3])) +                         \
             ((pf[4] + pf[5]) + (pf[6] + pf[7]));                          \
    bf16x2 p0, p1, p2, p3;                                                 \
    p0[0] = (bf16_t)pf[0]; p0[1] = (bf16_t)pf[1];                          \
    p1[0] = (bf16_t)pf[2]; p1[1] = (bf16_t)pf[3];                          \
    p2[0] = (bf16_t)pf[4]; p2[1] = (bf16_t)pf[5];                          \
    p3[0] = (bf16_t)pf[6]; p3[1] = (bf16_t)pf[7];                          \
    unsigned int sA = __builtin_bit_cast(unsigned int, p0);                \
    unsigned int sB = __builtin_bit_cast(unsigned int, p1);                \
    unsigned int sC = __builtin_bit_cast(unsigned int, p2);                \
    unsigned int sD = __builtin_bit_cast(unsigned int, p3);                \
    permswap32(sA, sC);                                                    \
    permswap32(sB, sD);                                                    \
    u32x4 fv;                                                              \
    fv[0] = sA; fv[1] = sB; fv[2] = sC; fv[3] = sD;                        \
    (PDST_EXPR) = __builtin_bit_cast(bf16x8, fv);                          \
  }

// one PV chunk: 16 keys (frag PP[C]) x all 128 d -> 4 MFMA
#define PVC(PP, C)                                                         \
  _Pragma("unroll")                                                        \
  for (int ot = 0; ot < 4; ++ot) {                                         \
    bf16x8 vb = *(const bf16x8*)&vt3[vp][(C) * 2 + h][ot * 32 + n32][0];   \
    o_acc[ot] = __builtin_amdgcn_mfma_f32_32x32x16_bf16(PP[C], vb, o_acc[ot], 0, 0, 0); \
  }

// pipelined body for iteration IT>=1: DMA(IT+1); QK^T(IT) from kt2[KC]
// (sacc0/sacc1 chains interleaved); then 4x [PV(IT-1) chunk || exp(IT)
// chunk]; barrier.  KC is a literal.
#define FBODY(IT, PPREV, PCUR, KC)                                         \
  {                                                                        \
    const int it_ = (IT);                                                  \
    if (it_ + 1 < nit) {                                                   \
      const int ntile = tile0 + it_ + 1;                                   \
      _Pragma("unroll")                                                    \
      for (int t = 0; t < 2; ++t) {                                        \
        const int rr = rr0 + t;                                            \
        load_lds16(Kb + ((size_t)(ntile * 16 + rr) * 64 + lane) * 8,       \
                   (char*)&kt2[(KC) ^ 1][0][0][0] + rr * 1024);            \
        load_lds16(VT + ((size_t)(ntile * 8 + (rr >> 1)) * 128 + (rr & 1) * 64 + lane) * 8, \
                   (char*)&vt3[vd][0][0][0] + rr * 1024);                  \
      }                                                                    \
    }                                                                      \
    f32x16 sacc0, sacc1;                                                   \
    _Pragma("unroll")                                                      \
    for (int e = 0; e < 16; ++e) { sacc0[e] = 0.f; sacc1[e] = 0.f; }       \
    _Pragma("unroll")                                                      \
    for (int kk = 0; kk < 8; ++kk) {                                       \
      bf16x8 af0 = *(const bf16x8*)&kt2[KC][2 * kk + h][n32][0];           \
      sacc0 = __builtin_amdgcn_mfma_f32_32x32x16_bf16(af0, qf[kk], sacc0, 0, 0, 0); \
      bf16x8 af1 = *(const bf16x8*)&kt2[KC][2 * kk + h][32 + n32][0];      \
      sacc1 = __builtin_amdgcn_mfma_f32_32x32x16_bf16(af1, qf[kk], sacc1, 0, 0, 0); \
    }                                                                      \
    PVC(PPREV, 0) EXPPACK1(sacc0, 0, PCUR[0])                              \
    PVC(PPREV, 1) EXPPACK1(sacc0, 1, PCUR[1])                              \
    PVC(PPREV, 2) EXPPACK1(sacc1, 0, PCUR[2])                              \
    PVC(PPREV, 3) EXPPACK1(sacc1, 1, PCUR[3])                              \
    vp = (vp + 1 == 3) ? 0 : vp + 1;                                       \
    vd = (vd + 1 == 3) ? 0 : vd + 1;                                       \
    __syncthreads();                                                       \
  }

  // ---- prologue: DMA tile0 -> kt[0], vt[0] ----
#pragma unroll
  for (int t = 0; t < 2; ++t) {
    const int rr = rr0 + t;
    load_lds16(Kb + ((size_t)(tile0 * 16 + rr) * 64 + lane) * 8,
               (char*)&kt2[0][0][0][0] + rr * 1024);
    load_lds16(VT + ((size_t)(tile0 * 8 + (rr >> 1)) * 128 + (rr & 1) * 64 + lane) * 8,
               (char*)&vt3[0][0][0][0] + rr * 1024);
  }
  __syncthreads();

  // ---- peel it=0: DMA tile1 -> kt[1], vt[1]; QK^T(0); exp -> paA ----
  {
    if (nit > 1) {
      const int ntile = tile0 + 1;
#pragma unroll
      for (int t = 0; t < 2; ++t) {
        const int rr = rr0 + t;
        load_lds16(Kb + ((size_t)(ntile * 16 + rr) * 64 + lane) * 8,
                   (char*)&kt2[1][0][0][0] + rr * 1024);
        load_lds16(VT + ((size_t)(ntile * 8 + (rr >> 1)) * 128 + (rr & 1) * 64 + lane) * 8,
                   (char*)&vt3[1][0][0][0] + rr * 1024);
      }
    }
    f32x16 sacc0, sacc1;
#pragma unroll
    for (int e = 0; e < 16; ++e) { sacc0[e] = 0.f; sacc1[e] = 0.f; }
#pragma unroll
    for (int kk = 0; kk < 8; ++kk) {
      bf16x8 af0 = *(const bf16x8*)&kt2[0][2 * kk + h][n32][0];
      sacc0 = __builtin_amdgcn_mfma_f32_32x32x16_bf16(af0, qf[kk], sacc0, 0, 0, 0);
      bf16x8 af1 = *(const bf16x8*)&kt2[0][2 * kk + h][32 + n32][0];
      sacc1 = __builtin_amdgcn_mfma_f32_32x32x16_bf16(af1, qf[kk], sacc1, 0, 0, 0);
    }
    EXPPACK1(sacc0, 0, paA[0])
    EXPPACK1(sacc0, 1, paA[1])
    EXPPACK1(sacc1, 0, paA[2])
    EXPPACK1(sacc1, 1, paA[3])
    __syncthreads();
  }

  int vp = 0;   // vt3 index holding tile (IT-1) for IT=1
  int vd = 2;   // vt3 index receiving tile (IT+1) for IT=1

  // nit is always even; bodies 1..nit-2 in pairs (KC literal by parity),
  // leftover body nit-1 (odd -> KC=1).
  for (int it = 1; it + 1 <= nit - 1; it += 2) {
    FBODY(it, paA, paB, 1)
    FBODY(it + 1, paB, paA, 0)
  }
  FBODY(nit - 1, paA, paB, 1)

  // ---- tail: PV(nit-1) using paB, vt3[vp] ----
#pragma unroll
  for (int C = 0; C < 4; ++C) {
#pragma unroll
    for (int ot = 0; ot < 4; ++ot) {
      bf16x8 vb = *(const bf16x8*)&vt3[vp][C * 2 + h][ot * 32 + n32][0];
      o_acc[ot] = __builtin_amdgcn_mfma_f32_32x32x16_bf16(paB[C], vb, o_acc[ot], 0, 0, 0);
    }
  }

#undef FBODY
#undef PVC
#undef EXPPACK1

  // ---- epilogue: O block store + L (all intra-wave) ----
  {
    float* op = Opart + ((size_t)sp * SEQ + qbase + w * 32) * HD;
#pragma unroll
    for (int ot = 0; ot < 4; ++ot)
#pragma unroll
      for (int reg = 0; reg < 16; ++reg) {
        const int row = (reg & 3) + 8 * (reg >> 2) + 4 * h;
        op[row * HD + ot * 32 + n32] = o_acc[ot][reg];
      }
    float l = l_acc + __shfl_xor(l_acc, 32);   // combine the two key-halves
    if (lane < 32)
      Lpart[(size_t)sp * SEQ + qbase + w * 32 + n32] = l;
  }
}

// ---------------- combine: out = sum_s O_s / sum_s l_s ----------------
__global__ __launch_bounds__(256) void combine_kernel(const float* __restrict__ Opart,
                                                      const float* __restrict__ Lpart,
                                                      float* __restrict__ out, int ksplit) {
  const int tid = (int)threadIdx.x;
  const int row = (int)blockIdx.x * 8 + (tid >> 5);
  const int c0 = (tid & 31) * 4;
  float lsum = 0.f;
  for (int s = 0; s < ksplit; ++s) lsum += Lpart[(size_t)s * SEQ + row];
  f32x4 acc;
#pragma unroll
  for (int e = 0; e < 4; ++e) acc[e] = 0.f;
  for (int s = 0; s < ksplit; ++s) {
    f32x4 o = *(const f32x4*)&Opart[((size_t)s * SEQ + row) * HD + c0];
#pragma unroll
    for (int e = 0; e < 4; ++e) acc[e] += o[e];
  }
  const float inv = 1.0f / lsum;
  f32x4 res;
#pragma unroll
  for (int e = 0; e < 4; ++e) res[e] = acc[e] * inv;
  *(f32x4*)&out[(size_t)row * HD + c0] = res;
}

extern "C" void kernel_launch(void* const* d_in, const int* in_sizes, int n_in,
                              void* d_out, int out_size, void* d_ws, size_t ws_size,
                              hipStream_t stream) {
  const float* Q = (const float*)d_in[0];
  const float* K = (const float*)d_in[1];
  const float* V = (const float*)d_in[2];
  float* out = (float*)d_out;

  int ksplit = 8, kshift = 3;
  while (ksplit > 1) {
    size_t need = (size_t)ksplit * SEQ * HD * 4
                + (size_t)ksplit * SEQ * 4
                + (size_t)SEQ * HD * 2 * 2;
    if (need <= ws_size) break;
    ksplit >>= 1; kshift--;
  }

  char* ws = (char*)d_ws;
  float* Opart = (float*)ws;
  float* Lpart = (float*)(ws + (size_t)ksplit * SEQ * HD * 4);
  bf16_t* Kb = (bf16_t*)(ws + (size_t)ksplit * SEQ * HD * 4 + (size_t)ksplit * SEQ * 4);
  bf16_t* VT = Kb + (size_t)SEQ * HD;

  const int nit = SEQ / (ksplit * BN);

  prep_kernel<<<768, 256, 0, stream>>>(K, V, Kb, VT);
  fattn_kernel<<<NQT * ksplit, THREADS, 0, stream>>>(Q, Kb, VT, Opart, Lpart, kshift, nit);
  combine_kernel<<<SEQ / 8, 256, 0, stream>>>(Opart, Lpart, out, ksplit);
}